// Round 6
// baseline (674.249 us; speedup 1.0000x reference)
//
#include <hip/hip_runtime.h>
#include <stdint.h>

#define BB 256
#define TT 2048
#define KK 64
#define CHUNK 64
#define NCHUNK (TT / CHUNK)   // 32
#define WLEN 128
#define NWIN (TT / WLEN)      // 16
#define NEG_INF_F (-10000.0f)

// DPP cross-lane helpers (free VALU permutes within 16-lane rows)
#define DPP_XOR1 0xB1   // quad_perm [1,0,3,2]
#define DPP_XOR2 0x4E   // quad_perm [2,3,0,1]
#define DPP_HMIR 0x141  // row_half_mirror (== xor4 once quads reduced)
#define DPP_ROR8 0x128  // row_ror:8 (pairs 8-halves of each 16-lane row)

template <int CTRL>
__device__ __forceinline__ float dpp_f(float x) {
    return __int_as_float(__builtin_amdgcn_update_dpp(
        0, __float_as_int(x), CTRL, 0xF, 0xF, true));
}
template <int CTRL>
__device__ __forceinline__ int dpp_i(int x) {
    return __builtin_amdgcn_update_dpp(0, x, CTRL, 0xF, 0xF, true);
}

// LDS-only barrier: never drains vmcnt (bp stores / window loads stay in flight)
__device__ __forceinline__ void lds_barrier() {
    asm volatile("s_waitcnt lgkmcnt(0)\n\ts_barrier" ::: "memory");
}

__device__ __forceinline__ void gload_lds16(const void* g, void* l) {
    __builtin_amdgcn_global_load_lds(
        (const __attribute__((address_space(1))) void*)g,
        (__attribute__((address_space(3))) void*)l, 16, 0, 0);
}

__global__ __launch_bounds__(1024)
void viterbi_fwd_bt(const float* __restrict__ feats,
                    const float* __restrict__ trans,
                    const int* __restrict__ start_tag_p,
                    const int* __restrict__ stop_tag_p,
                    float* __restrict__ out,
                    unsigned char* __restrict__ bp_ws)
{
    const int b    = blockIdx.x;
    const int tid  = threadIdx.x;
    const int lane = tid & 63;
    const int w    = __builtin_amdgcn_readfirstlane(tid >> 6);  // wave 0..15
    const int g    = lane >> 4;        // row group within wave (4 rows/wave)
    const int j    = lane & 15;        // p-chunk within row (16 chunks of 4)
    const int n    = w * 4 + g;        // owned output row
    const int pbase = j * 4;
    const bool jz  = (j == 0);

    const int start_tag = *start_tag_p;
    const int stop_tag  = *stop_tag_p;

    __shared__ float fv_lds[2][KK];          // double-buffered Viterbi variables
    __shared__ float feat_lds[2][WLEN][KK];  // 64KB feat window double buffer
    __shared__ int   cmap[NCHUNK][KK];       // composed backpointer maps
    __shared__ int   be_lds[NCHUNK];
    __shared__ int   bl_lds;

    const float* fb = feats + (size_t)b * TT * KK;
    unsigned char* bpb = bp_ws + (size_t)b * TT * KK;

    // async window stage: wave w fills its 2KB slice, 2 x 1KB issues (linear)
    auto issue_win = [&](int widx, int bufsel) {
        const char* gsrc = (const char*)(fb + (size_t)widx * WLEN * KK)
                         + w * 2048 + lane * 16;
        char* ldst = (char*)&feat_lds[bufsel][0][0] + w * 2048;
        gload_lds16(gsrc, ldst);
        gload_lds16(gsrc + 1024, ldst + 1024);
    };
    issue_win(0, 0);   // window 0 in flight ASAP

    // per-lane transition fragment: trans[n][pbase .. pbase+3]
    const float4 tA = *(const float4*)&trans[n * KK + pbase];
    const float tstop = trans[stop_tag * KK + lane];
    const int c0 = pbase + 0, c1 = pbase + 1, c2 = pbase + 2, c3 = pbase + 3;

    if (tid < KK) fv_lds[0][tid] = (tid == start_tag) ? 0.0f : NEG_INF_F;

    __syncthreads();   // drains vmcnt(0): window 0 resident + fv init visible
    issue_win(1, 1);   // window 1 in flight across window 0's 128 steps

    // previous-step state for the deferred argmax
    float4 pA = make_float4(0, 0, 0, 0);
    float  pmax = 0.0f;

    auto step = [&](int t, const float* frow) {
        // issue LDS reads for step t (latency overlapped by deferred argmax)
        const float4 fa = *(const float4*)&fv_lds[t & 1][pbase];
        const float featval = frow[n];     // 16-lane broadcast, conflict-free

        // deferred argmax + bp store for step t-1 (register-only inputs)
        if (t > 0) {
            const int s0 = (pA.x == pmax) ? c0 : 255;
            const int s1 = (pA.y == pmax) ? c1 : 255;
            const int s2 = (pA.z == pmax) ? c2 : 255;
            const int s3 = (pA.w == pmax) ? c3 : 255;
            int idx = min(min(min(s0, s1), s2), s3);   // v_min3 + v_min
            idx = min(idx, dpp_i<DPP_XOR1>(idx));
            idx = min(idx, dpp_i<DPP_XOR2>(idx));
            idx = min(idx, dpp_i<DPP_HMIR>(idx));
            idx = min(idx, dpp_i<DPP_ROR8>(idx));      // smallest matching p
            if (jz) bpb[(size_t)(t - 1) * KK + n] = (unsigned char)idx;
        }

        // scores for this lane's 4 p's
        float4 vA;
        vA.x = fa.x + tA.x; vA.y = fa.y + tA.y;
        vA.z = fa.z + tA.z; vA.w = fa.w + tA.w;

        // in-lane max (v_max3 + v_max)
        float m = fmaxf(fmaxf(fmaxf(vA.x, vA.y), vA.z), vA.w);
        // cross-lane max over the 16 lanes of this row (free DPP)
        m = fmaxf(m, dpp_f<DPP_XOR1>(m));
        m = fmaxf(m, dpp_f<DPP_XOR2>(m));
        m = fmaxf(m, dpp_f<DPP_HMIR>(m));
        m = fmaxf(m, dpp_f<DPP_ROR8>(m));

        if (jz) fv_lds[(t + 1) & 1][n] = m + featval;  // 4 consecutive dwords

        pA = vA; pmax = m;
        lds_barrier();
    };

    for (int W = 0; W < NWIN; ++W) {
        const float (*fw)[KK] = feat_lds[W & 1];
        const int base = W * WLEN;
        for (int tt = 0; tt < WLEN; tt += 4) {
            step(base + tt + 0, fw[tt + 0]);
            step(base + tt + 1, fw[tt + 1]);
            step(base + tt + 2, fw[tt + 2]);
            step(base + tt + 3, fw[tt + 3]);
        }
        // boundary: ensure window W+1 (issued one window ago) is resident
        asm volatile("s_waitcnt vmcnt(0)" ::: "memory");
        __builtin_amdgcn_s_barrier();
        if (W + 2 < NWIN) issue_win(W + 2, W & 1);   // overwrite just-read buffer
    }

    // trailing argmax for t = TT-1
    {
        const int s0 = (pA.x == pmax) ? c0 : 255;
        const int s1 = (pA.y == pmax) ? c1 : 255;
        const int s2 = (pA.z == pmax) ? c2 : 255;
        const int s3 = (pA.w == pmax) ? c3 : 255;
        int idx = min(min(min(s0, s1), s2), s3);
        idx = min(idx, dpp_i<DPP_XOR1>(idx));
        idx = min(idx, dpp_i<DPP_XOR2>(idx));
        idx = min(idx, dpp_i<DPP_HMIR>(idx));
        idx = min(idx, dpp_i<DPP_ROR8>(idx));
        if (jz) bpb[(size_t)(TT - 1) * KK + n] = (unsigned char)idx;
    }

    __syncthreads();   // full drain: all bp stores visible block-wide

    // ---- chunk-map composition: wave w composes chunks 2w, 2w+1 ----
    {
        const int cc = w * 2;
        const unsigned char* q0 = bpb + (size_t)(cc + 0) * CHUNK * KK + lane;
        const unsigned char* q1 = bpb + (size_t)(cc + 1) * CHUNK * KK + lane;
        int M0 = lane, M1 = lane;
        int a0 = q0[0], a1 = q1[0];
        int b0 = q0[KK], b1 = q1[KK];
        for (int t = 0; t < CHUNK; t += 2) {
            int n0 = 0, n1 = 0, m0 = 0, m1 = 0;
            if (t + 2 < CHUNK) {
                n0 = q0[(t + 2) * KK]; n1 = q1[(t + 2) * KK];
                m0 = q0[(t + 3) * KK]; m1 = q1[(t + 3) * KK];
            }
            M0 = __shfl(M0, a0); M1 = __shfl(M1, a1);
            M0 = __shfl(M0, b0); M1 = __shfl(M1, b1);
            a0 = n0; a1 = n1; b0 = m0; b1 = m1;
        }
        cmap[cc + 0][lane] = M0; cmap[cc + 1][lane] = M1;
    }

    // ---- terminal argmax (wave 0, butterfly, first-max tie-break) ----
    if (w == 0) {
        float bv = fv_lds[TT & 1][lane] + tstop;   // TT even -> buffer 0
        int bi = lane;
#pragma unroll
        for (int off = 1; off < 64; off <<= 1) {
            const float ov = __shfl_xor(bv, off);
            const int   oi = __shfl_xor(bi, off);
            const bool take = (ov > bv) || (ov == bv && oi < bi);
            bv = take ? ov : bv;
            bi = take ? oi : bi;
        }
        if (lane == 0) { out[b] = bv; bl_lds = bi; }
    }
    __syncthreads();

    // ---- chunk-boundary tags via composed maps (serial, 32 LDS hops) ----
    if (tid == 0) {
        int x = bl_lds;
        be_lds[NCHUNK - 1] = x;
        for (int c = NCHUNK - 1; c >= 1; --c) {
            x = cmap[c][x];
            be_lds[c - 1] = x;
        }
    }
    __syncthreads();

    // ---- parallel interior backtrace (32 chunks, one lane each) ----
    if (tid < NCHUNK) {
        const int c = tid;
        int x = be_lds[c];
        float* po = out + BB + (size_t)b * TT;
        for (int t = (c + 1) * CHUNK - 1; t >= c * CHUNK; --t) {
            po[t] = (float)x;
            x = (int)bpb[(size_t)t * KK + x];
        }
    }
}

extern "C" void kernel_launch(void* const* d_in, const int* in_sizes, int n_in,
                              void* d_out, int out_size, void* d_ws, size_t ws_size,
                              hipStream_t stream) {
    const float* feats = (const float*)d_in[0];
    const float* trans = (const float*)d_in[1];
    const int* start_tag = (const int*)d_in[2];
    const int* stop_tag  = (const int*)d_in[3];
    float* out = (float*)d_out;
    unsigned char* bp = (unsigned char*)d_ws;   // B*T*K = 33.5 MB backpointers

    viterbi_fwd_bt<<<BB, 1024, 0, stream>>>(feats, trans, start_tag, stop_tag, out, bp);
}